// Round 4
// baseline (638.757 us; speedup 1.0000x reference)
//
#include <hip/hip_runtime.h>

// Orient_Conv: 3x3 orientation-gated conv, 4 orientations + per-pixel argmax.
// B=4, CIN=COUT=32, H=W=128, pad=1.
//
// Gate identity (C=cos(wr), S=sin(wr), r0=cos(th), r1=sin(th)):
//   u = C*r0+S*r1, vv = C*r1-S*r0
//   gates: o0=relu(u), o1=relu(vv), o2=relu(-u), o3=relu(-vv)
//   products: t0=f*relu(u), t1=f*relu(vv), t2 = t0 - f*u (=f*relu(-u)),
//             t3 = t1 - f*vv  -> 14-op packed core, 2 px/v2f.
// Rotated weights at tap (i,j): w0=w[i][j], w1=w[2-j][i], w2=w[2-i][2-j],
//   w3=w[j][2-i].
//
// R14 = R13 + register row-prefetch (RA/RB ping-pong, DS_READ-pinned) funded
// by global_load_lds staging. R13 post-mortem: VALU-busy constant ~163 us
// across R11-R13; remaining idle traced to the 96 per-row ds_read_b128
// bursts consumed immediately (full lgkmcnt wait, ~120cyc, only ~3
// waves/SIMD to cover) with the LDS pipe itself ~92 us/CU (co-critical with
// ~120 us VALU). Fixes:
//  (a) RA/RB: step s loads row s+1's 6 float4s into regs (pinned with
//      sched_group_barrier(DS_READ,6)) while computing row s -> counted
//      lgkmcnt with a full row-compute of slack.
//  (b) +48 VGPR would cross the 128-reg 2-block/CU cliff, so staging moves
//      to __builtin_amdgcn_global_load_lds: LDS slot map is linear in
//      s = tid + k*512 with the pair-interleave permutation carried in the
//      per-lane GLOBAL address (goff) - the legal gll pattern (linear dest
//      + pre-swizzled source + swizzled read). Deletes tF/tA/tB + msk/sidx
//      (~34 regs) and all staging VALU. OOB halo lanes fixed up with
//      ds_write zeros after a vmcnt(0) drain before each barrier.
//  (c) PLANE_ 1636 -> 1668 (>= 1664) so a full-wave DMA overrun in the
//      partial round-3 stays inside the plane pad; %32==4 keeps the
//      bank stagger. launch_bounds(512,4) caps VGPR at 128 (2 blocks/CU).
// Accumulation order unchanged -> bitwise-identical output vs R13.

typedef float v2f __attribute__((ext_vector_type(2)));

#define B_    4
#define CIN_  32
#define COUT_ 32
#define H_    128
#define W_    128
#define HW_   (H_ * W_)
#define OUTSZ_ (B_ * COUT_ * H_ * W_)

// tab layout: [cc][tap][oc][8] = {C,S,w0,w1,w2,w3,0,0}; 294912 B
__global__ __launch_bounds__(256)
void build_wtab(const float* __restrict__ w, const float* __restrict__ wr,
                float* __restrict__ tab)
{
    int idx = blockIdx.x * 256 + threadIdx.x;   // ((cc*9+tap)<<5)|oc
    if (idx >= CIN_ * 9 * COUT_) return;        // 9216
    int oc  = idx & 31;
    int t2  = idx >> 5;
    int tap = t2 % 9;
    int cc  = t2 / 9;
    int i = tap / 3, j = tap - i * 3;
    int base = (oc * CIN_ + cc) * 9;
    float w0 = w[base + i * 3 + j];
    float w1 = w[base + (2 - j) * 3 + i];
    float w2 = w[base + (2 - i) * 3 + (2 - j)];
    float w3 = w[base + j * 3 + (2 - i)];
    float S, C;
    sincosf(wr[base + i * 3 + j], &S, &C);
    float* dst = tab + (size_t)idx * 8;
    dst[0] = C;  dst[1] = S;
    dst[2] = w0; dst[3] = w1;
    dst[4] = w2; dst[5] = w3;
    dst[6] = 0.0f; dst[7] = 0.0f;
}

#define NC_    8                      // channels staged per buffer
#define NG_    (CIN_ / NC_)           // 4 groups
#define ROWF_  68                     // floats per row = 34 pairs x 2
#define CLSTR_ (3 * ROWF_)            // 204 floats per staged channel
#define USED_  (NC_ * CLSTR_)         // 1632 slots per plane
#define PLANE_ 1668                   // pad >=1664 (DMA overrun slack); %32==4
#define NBUF_  (3 * PLANE_)           // floats per buffer (f,r0,r1 planes)

struct WRow { float4 a0, a1, a2; float2 b0, b1, b2; };       // 18 floats
struct RRow { float4 f0, f1, a0, a1, b0, b1; };              // 24 floats

// Load one row-step's 6 weight words (taps 3r..3r+2), pinned so the
// scheduler cannot sink them into the compute below. Anchor = middle tap.
#define LOAD_WROW(Wd) do {                                                  \
    const float* _wp = wanchor + soff;                                      \
    (Wd).a0 = *reinterpret_cast<const float4*>(_wp - 256);                  \
    (Wd).b0 = *reinterpret_cast<const float2*>(_wp - 252);                  \
    (Wd).a1 = *reinterpret_cast<const float4*>(_wp);                        \
    (Wd).b1 = *reinterpret_cast<const float2*>(_wp + 4);                    \
    (Wd).a2 = *reinterpret_cast<const float4*>(_wp + 256);                  \
    (Wd).b2 = *reinterpret_cast<const float2*>(_wp + 260);                  \
    soff += 768;                                                            \
    soff = (soff < 72960) ? soff : 72960;  /* clamp final dead prefetch */  \
    __builtin_amdgcn_sched_group_barrier(0x020, 6, 0); /* 6 VMEM reads */   \
} while (0)

// Load one LDS row (6 x ds_read_b128) into an RRow, pinned at issue point.
#define RLOAD(Rd, RB_, CL, II) do {                                         \
    const float* _rp = (RB_) + (CL) * CLSTR_ + (II) * ROWF_ + (p << 1);     \
    (Rd).f0 = *reinterpret_cast<const float4*>(_rp);                        \
    (Rd).f1 = *reinterpret_cast<const float4*>(_rp + 4);                    \
    (Rd).a0 = *reinterpret_cast<const float4*>(_rp + PLANE_);               \
    (Rd).a1 = *reinterpret_cast<const float4*>(_rp + PLANE_ + 4);           \
    (Rd).b0 = *reinterpret_cast<const float4*>(_rp + 2 * PLANE_);           \
    (Rd).b1 = *reinterpret_cast<const float4*>(_rp + 2 * PLANE_ + 4);       \
    __builtin_amdgcn_sched_group_barrier(0x100, 6, 0); /* 6 DS reads */     \
} while (0)

#define CORE_TAP(W4, W2, JJ) do {                                           \
    v2f _C2  = {(W4).x, (W4).x};                                            \
    v2f _S2  = {(W4).y, (W4).y};                                            \
    v2f _w0  = {(W4).z, (W4).z};                                            \
    v2f _w1  = {(W4).w, (W4).w};                                            \
    v2f _w2  = {(W2).x, (W2).x};                                            \
    v2f _w3  = {(W2).y, (W2).y};                                            \
    _Pragma("unroll")                                                       \
    for (int _q = 0; _q < 2; ++_q) {                                        \
        v2f _f  = _fP[_q + (JJ)];                                           \
        v2f _r0 = _aP[_q + (JJ)];                                           \
        v2f _r1 = _bP[_q + (JJ)];                                           \
        v2f _m1 = _S2 * _r1;                                                \
        v2f _u  = __builtin_elementwise_fma(_C2, _r0, _m1);                 \
        v2f _m2 = _S2 * _r0;                                                \
        v2f _vv = __builtin_elementwise_fma(_C2, _r1, -_m2);                \
        v2f _g0 = __builtin_elementwise_max(_u,  (v2f)(0.0f));              \
        v2f _g1 = __builtin_elementwise_max(_vv, (v2f)(0.0f));              \
        v2f _t0 = _f * _g0;                                                 \
        v2f _t1 = _f * _g1;                                                 \
        v2f _t2 = __builtin_elementwise_fma(_f, -_u,  _t0);                 \
        v2f _t3 = __builtin_elementwise_fma(_f, -_vv, _t1);                 \
        acc[_q][0] = __builtin_elementwise_fma(_t0, _w0, acc[_q][0]);       \
        acc[_q][1] = __builtin_elementwise_fma(_t1, _w1, acc[_q][1]);       \
        acc[_q][2] = __builtin_elementwise_fma(_t2, _w2, acc[_q][2]);       \
        acc[_q][3] = __builtin_elementwise_fma(_t3, _w3, acc[_q][3]);       \
    }                                                                       \
} while (0)

#define COMPUTE_R(Wr, Rs) do {                                              \
    v2f _fP[4] = {{(Rs).f0.x,(Rs).f0.y},{(Rs).f0.z,(Rs).f0.w},              \
                  {(Rs).f1.x,(Rs).f1.y},{(Rs).f1.z,(Rs).f1.w}};             \
    v2f _aP[4] = {{(Rs).a0.x,(Rs).a0.y},{(Rs).a0.z,(Rs).a0.w},              \
                  {(Rs).a1.x,(Rs).a1.y},{(Rs).a1.z,(Rs).a1.w}};             \
    v2f _bP[4] = {{(Rs).b0.x,(Rs).b0.y},{(Rs).b0.z,(Rs).b0.w},              \
                  {(Rs).b1.x,(Rs).b1.y},{(Rs).b1.z,(Rs).b1.w}};             \
    CORE_TAP((Wr).a0, (Wr).b0, 0);                                          \
    CORE_TAP((Wr).a1, (Wr).b1, 1);                                          \
    CORE_TAP((Wr).a2, (Wr).b2, 2);                                          \
} while (0)

// STEP: prefetch next weight-row, prefetch next data-row, compute current.
#define STEP_RW(WLD, WUSE, RLD, RUSE, RB_, CL, II) do {                     \
    LOAD_WROW(WLD);                                                         \
    RLOAD(RLD, RB_, CL, II);                                                \
    COMPUTE_R(WUSE, RUSE);                                                  \
} while (0)

#define STEP_LAST(WLD, WUSE, RUSE) do {                                     \
    LOAD_WROW(WLD);                                                         \
    COMPUTE_R(WUSE, RUSE);                                                  \
} while (0)

// Async-stage group GI into buffer DSTBASE via global_load_lds.
// LDS dest is linear (slot = k*512 + tid); the pair-interleave + halo
// permutation is carried entirely in the per-lane global offset goff[k].
// Round 3 covers slots 1536..1631 (tid<96); waves 2..7 skip via execz.
#define STAGE_GLL(GI, DSTBASE) do {                                         \
    const int _gb = chanBase + (GI) * (NC_ * HW_);                          \
    float* _db = (DSTBASE);                                                 \
    _Pragma("unroll")                                                       \
    for (int _k = 0; _k < 4; ++_k) {                                        \
        if (_k < 3 || tid < 96) {                                           \
            float* _l = _db + (_k << 9) + wvbase;                           \
            const float* _gf = f  + _gb + goff[_k];                         \
            const float* _ga = r0 + _gb + goff[_k];                         \
            const float* _gr = r1 + _gb + goff[_k];                         \
            __builtin_amdgcn_global_load_lds(                               \
                (const __attribute__((address_space(1))) void*)_gf,         \
                (__attribute__((address_space(3))) void*)(_l), 4, 0, 0);    \
            __builtin_amdgcn_global_load_lds(                               \
                (const __attribute__((address_space(1))) void*)_ga,         \
                (__attribute__((address_space(3))) void*)(_l + PLANE_), 4, 0, 0); \
            __builtin_amdgcn_global_load_lds(                               \
                (const __attribute__((address_space(1))) void*)_gr,         \
                (__attribute__((address_space(3))) void*)(_l + 2 * PLANE_), 4, 0, 0); \
        }                                                                   \
    }                                                                       \
    __builtin_amdgcn_sched_group_barrier(0x010, 12, 0);                     \
} while (0)

// Zero the OOB halo slots after the DMA lands (post vmcnt(0), pre-barrier).
#define FIXUP(DSTBASE) do {                                                 \
    float* _db = (DSTBASE);                                                 \
    _Pragma("unroll")                                                       \
    for (int _k = 0; _k < 4; ++_k) {                                        \
        int _s = tid + (_k << 9);                                           \
        if (_s < USED_ && !((okbits >> _k) & 1)) {                          \
            _db[_s] = 0.0f;                                                 \
            _db[PLANE_ + _s] = 0.0f;                                        \
            _db[2 * PLANE_ + _s] = 0.0f;                                    \
        }                                                                   \
    }                                                                       \
} while (0)

__global__ __launch_bounds__(512, 4)
void orient_conv_kernel(const float* __restrict__ f,
                        const float* __restrict__ r0,
                        const float* __restrict__ r1,
                        const float* __restrict__ tab,
                        float* __restrict__ out)
{
    // Double-buffered: planes 0=f, 1=r0, 2=r1 per buffer. Within plane:
    // [cl(8)][row(3)][pairslot(68)]; pairslot = c01*2 + s holds col c01+32*s.
    __shared__ float sm[2 * NBUF_];    // 40032 B; 2 blocks/CU

    const int tid    = threadIdx.x;
    const int oc     = tid & 31;
    const int pxg    = tid >> 5;           // 0..15
    const int p      = pxg << 1;           // even pair index 0..30
    const int wvbase = tid & ~63;          // wave-uniform slot base
    // XCD-aware bijective swizzle: 8 XCDs, nwg=1024, 1024%8==0.
    const int obid  = blockIdx.x;
    const int bid   = (obid & 7) * ((B_ * H_ * 2) >> 3) + (obid >> 3);
    const int b     = bid >> 8;
    const int rem   = bid & 255;
    const int h     = rem >> 1;
    const int wbase = (rem & 1) << 6;      // 0 or 64

    // ---- staging descriptors: per-lane global offset + validity bit ----
    int      goff[4];
    unsigned okbits = 0;
#pragma unroll
    for (int k = 0; k < 4; ++k) {
        int s = tid + (k << 9);
        int ok = 0, go = 0;
        if (s < USED_) {
            int cl  = s / CLSTR_;
            int r2  = s - cl * CLSTR_;
            int row = r2 / ROWF_;
            int q2  = r2 - row * ROWF_;     // 0..67
            int col = (q2 >> 1) + ((q2 & 1) << 5);   // c01 + 32*s -> 0..65
            int gh = h + row - 1;
            int gw = wbase + col - 1;
            ok = ((unsigned)gh < (unsigned)H_) & ((unsigned)gw < (unsigned)W_);
            go = ok ? (cl * HW_ + gh * W_ + gw) : 0;
        }
        goff[k] = go;
        okbits |= (unsigned)ok << k;
    }
    const int chanBase = b * (CIN_ * HW_);

    v2f acc[2][4];                     // [pair q][orient]; elems = px, px+32
#pragma unroll
    for (int q = 0; q < 2; ++q)
#pragma unroll
        for (int o = 0; o < 4; ++o) acc[q][o] = (v2f)(0.0f);

    // ---- weight row-step pipeline state ----
    // row-step s = cc*3 + r, s in [0,95]; anchor = tap (3r+1) of cc.
    const float* wanchor = tab + (size_t)((1 << 5) | oc) * 8;  // s=0 anchor
    int soff = 0;
    WRow WA, WB;
    RRow RA, RB;
    LOAD_WROW(WA);                     // prologue: row-step 0 -> WA

    // ---- prologue staging: g0 -> buf0 (DMA), fixup, barrier ----
    STAGE_GLL(0, sm);
    asm volatile("s_waitcnt vmcnt(0)" ::: "memory");
    FIXUP(sm);
    __syncthreads();

#pragma unroll 1
    for (int g = 0; g < NG_; ++g) {
        float* cur = sm + (g & 1) * NBUF_;
        float* nxt = sm + ((g + 1) & 1) * NBUF_;

        // async-stage group g+1 into the other buffer (released by the
        // barrier ending group g-1); lands during this group's compute
        if (g + 1 < NG_) STAGE_GLL(g + 1, nxt);

        RLOAD(RA, cur, 0, 0);          // first row of this group

        // ---- 24 row-steps: weights + row data ping-pong one step ahead ----
#pragma unroll 1
        for (int cl = 0; cl < NC_ - 2; cl += 2) {   // cl = 0,2,4
            STEP_RW(WB, WA, RB, RA, cur, cl,     1);
            STEP_RW(WA, WB, RA, RB, cur, cl,     2);
            STEP_RW(WB, WA, RB, RA, cur, cl + 1, 0);
            STEP_RW(WA, WB, RA, RB, cur, cl + 1, 1);
            STEP_RW(WB, WA, RB, RA, cur, cl + 1, 2);
            STEP_RW(WA, WB, RA, RB, cur, cl + 2, 0);
        }
        // tail: cl = 6,7 (no prefetch past the group's last row)
        STEP_RW(WB, WA, RB, RA, cur, 6, 1);
        STEP_RW(WA, WB, RA, RB, cur, 6, 2);
        STEP_RW(WB, WA, RB, RA, cur, 7, 0);
        STEP_RW(WA, WB, RA, RB, cur, 7, 1);
        STEP_RW(WB, WA, RB, RA, cur, 7, 2);
        STEP_LAST(WA, WB, RB);

        // ---- drain this group's DMA, fix halo zeros, publish buffer ----
        if (g + 1 < NG_) {
            asm volatile("s_waitcnt vmcnt(0)" ::: "memory");
            FIXUP(nxt);
            __syncthreads();           // one barrier per group
        }
    }

    // ---- epilogue: max/argmax over orientations (first-max tie-break) ----
    const float cosv[4] = {1.0f, -4.37113883e-08f, -1.0f, 1.19248806e-08f};
    const float sinv[4] = {0.0f, 1.0f, -8.74227766e-08f, -1.0f};
#pragma unroll
    for (int q = 0; q < 2; ++q) {
#pragma unroll
        for (int k = 0; k < 2; ++k) {
            int wcol = wbase + p + q + (k << 5);
            float a0 = acc[q][0][k], a1 = acc[q][1][k];
            float a2 = acc[q][2][k], a3 = acc[q][3][k];
            float best = a0; int bi = 0;
            if (a1 > best) { best = a1; bi = 1; }
            if (a2 > best) { best = a2; bi = 2; }
            if (a3 > best) { best = a3; bi = 3; }
            size_t o = ((size_t)(b * COUT_ + oc) * H_ + h) * W_ + wcol;
            out[o]              = best;
            out[o + OUTSZ_]     = cosv[bi];
            out[o + 2 * OUTSZ_] = sinv[bi];
        }
    }
}

extern "C" void kernel_launch(void* const* d_in, const int* in_sizes, int n_in,
                              void* d_out, int out_size, void* d_ws, size_t ws_size,
                              hipStream_t stream)
{
    const float* f  = (const float*)d_in[0];
    const float* r0 = (const float*)d_in[1];
    const float* r1 = (const float*)d_in[2];
    const float* w  = (const float*)d_in[3];
    const float* wr = (const float*)d_in[4];
    float* out = (float*)d_out;
    float* tab = (float*)d_ws;    // 294912 B

    build_wtab<<<dim3(36), dim3(256), 0, stream>>>(w, wr, tab);
    orient_conv_kernel<<<dim3(B_ * H_ * 2), dim3(512), 0, stream>>>(
        f, r0, r1, tab, out);
}